// Round 2
// baseline (511.660 us; speedup 1.0000x reference)
//
#include <hip/hip_runtime.h>

#define PI_F 3.14159265358979323846f

// Reference quirk: reshape(B,3,8,8,4,4).mean((-1,-2)) pools over 16
// CONTIGUOUS floats of the flat (32*32) channel image (NOT spatial 4x4).
// Patch p in [0,64) covers flat elements [p*16, p*16+16) of each channel.
// output[b][p] = cos( mean_{c,i}(in[b][c][p*16+i]) * pi/255 - pi/2 ).
//
// One thread per output element. Each thread: 3 channels x 4 float4 = 12
// vector loads, each channel chunk 64B contiguous; consecutive threads hit
// adjacent 64B chunks -> fully coalesced, every byte read exactly once.
__global__ __launch_bounds__(256) void qa_pool_cos_kernel(
    const float* __restrict__ in, float* __restrict__ out, int total)
{
    int idx = blockIdx.x * blockDim.x + threadIdx.x;
    if (idx >= total) return;

    int b = idx >> 6;        // batch
    int p = idx & 63;        // patch 0..63

    const float* base = in + (size_t)b * 3072 + p * 16;

    float s = 0.0f;
#pragma unroll
    for (int c = 0; c < 3; ++c) {
        const float4* cb = reinterpret_cast<const float4*>(base + c * 1024);
#pragma unroll
        for (int q = 0; q < 4; ++q) {
            float4 v = cb[q];
            s += (v.x + v.y) + (v.z + v.w);
        }
    }

    float patch = s * (1.0f / 48.0f);
    float ang   = patch * (PI_F / 255.0f) - (PI_F * 0.5f);
    out[idx] = __cosf(ang);
}

extern "C" void kernel_launch(void* const* d_in, const int* in_sizes, int n_in,
                              void* d_out, int out_size, void* d_ws, size_t ws_size,
                              hipStream_t stream) {
    const float* in  = (const float*)d_in[0];
    float*       out = (float*)d_out;

    int total = out_size;            // B * 64
    int block = 256;
    int grid  = (total + block - 1) / block;

    qa_pool_cos_kernel<<<grid, block, 0, stream>>>(in, out, total);
}

// Round 3
// 502.701 us; speedup vs baseline: 1.0178x; 1.0178x over previous
//
#include <hip/hip_runtime.h>

#define PI_F 3.14159265358979323846f

// Reference: reshape(B,3,8,8,4,4).mean((-1,-2)).mean(ch) pools 16 CONTIGUOUS
// floats per patch per channel. out[b][p] = cos(mean48 * pi/255 - pi/2).
//
// Layout-optimal scheme: one block = one batch element (3072 floats = 12 KB
// = 768 float4). Thread tid loads float4 #tid -> each wave-instruction reads
// a contiguous 1 KB segment (16 full cache lines; zero address divergence).
// Aligned groups of 4 lanes hold one 16-float patch-channel chunk: butterfly
// shuffle (xor 1, xor 2) produces the patch-channel sum in all 4 lanes.
// Channels are 256 threads apart -> combine via 192 floats of LDS.
__global__ __launch_bounds__(768) void qa_pool_cos_kernel(
    const float4* __restrict__ in4, float* __restrict__ out)
{
    __shared__ float partial[192];   // [c][p] : 3 x 64

    int b   = blockIdx.x;
    int tid = threadIdx.x;           // 0..767

    float4 v = in4[(size_t)b * 768 + tid];
    float s = (v.x + v.y) + (v.z + v.w);

    // sum across aligned group of 4 lanes (16 floats = one patch-channel chunk)
    s += __shfl_xor(s, 1, 64);
    s += __shfl_xor(s, 2, 64);

    if ((tid & 3) == 0) {
        int c = tid >> 8;            // 0..2
        int p = (tid & 255) >> 2;    // 0..63
        partial[c * 64 + p] = s;
    }
    __syncthreads();

    if (tid < 64) {
        float total = partial[tid] + partial[64 + tid] + partial[128 + tid];
        float ang   = total * (1.0f / 48.0f) * (PI_F / 255.0f) - (PI_F * 0.5f);
        out[(size_t)b * 64 + tid] = __cosf(ang);
    }
}

extern "C" void kernel_launch(void* const* d_in, const int* in_sizes, int n_in,
                              void* d_out, int out_size, void* d_ws, size_t ws_size,
                              hipStream_t stream) {
    const float4* in4 = (const float4*)d_in[0];
    float*        out = (float*)d_out;

    int B = out_size / 64;           // 32768 batch elements
    qa_pool_cos_kernel<<<B, 768, 0, stream>>>(in4, out);
}